// Round 11
// baseline (1127.757 us; speedup 1.0000x reference)
//
#include <hip/hip_runtime.h>
#include <hip/hip_bf16.h>
#include <stdint.h>

typedef __hip_bfloat16 bf16_t;
typedef __attribute__((ext_vector_type(8))) short bf16x8;   // 8 bf16 = 4 VGPR
typedef __attribute__((ext_vector_type(4))) float f32x4;

#define DEV static __device__ __forceinline__

constexpr int kBB = 8, kL = 2048, kD = 1024;
constexpr int kM = kBB * kL;   // 16384 rows
constexpr int kSeg = 32, kP = 64;   // WKV: 32 segments x 64 steps

DEV float bf2f(unsigned short u) { return __uint_as_float((unsigned)u << 16); }
DEV unsigned short f2bf(float f) {
  unsigned u = __float_as_uint(f);
  return (unsigned short)((u + 0x7fffu + ((u >> 16) & 1u)) >> 16);  // RNE
}

// async global->LDS, 16B per lane. LDS dest is wave-uniform-base + lane*16.
DEV void gld16(const void* g, void* l) {
  const __attribute__((address_space(1))) unsigned* gp =
      (const __attribute__((address_space(1))) unsigned*)(uintptr_t)g;
  __attribute__((address_space(3))) unsigned* lp =
      (__attribute__((address_space(3))) unsigned*)(unsigned)(uintptr_t)l;
  __builtin_amdgcn_global_load_lds(gp, lp, 16, 0, 0);
}

// ------ weight 8-blocking: W[K][C] f32 -> Wb[K/8][C][8] bf16 (B-frag = 16B unit) ------
// Reads: 8 coalesced row segments; writes: 16B/thread contiguous. No transpose needed.
__global__ __launch_bounds__(256) void k_block8(
    const float* __restrict__ W, bf16_t* __restrict__ Wb, int C) {
  const int kb = blockIdx.y;
  const size_t c = (size_t)blockIdx.x * 256 + threadIdx.x;
  bf16x8 v;
#pragma unroll
  for (int j = 0; j < 8; ++j)
    v[j] = (short)f2bf(W[((size_t)kb * 8 + j) * C + c]);
  *(bf16x8*)(Wb + ((size_t)kb * C + c) * 8) = v;
}

// -------- fused LN(+stats)+shift+time-mix -> xk/xv/xr (bf16); one block per row --------
__global__ __launch_bounds__(256) void k_ln1f(
    const float* __restrict__ X, const float* __restrict__ g, const float* __restrict__ be,
    const float* __restrict__ mk, const float* __restrict__ mv, const float* __restrict__ mr,
    bf16_t* __restrict__ ok, bf16_t* __restrict__ ov, bf16_t* __restrict__ orr) {
  const int row = blockIdx.x;
  const int l = row & (kL - 1);
  const int i = threadIdx.x;                 // 4 floats per thread
  const bool hp = (l != 0);
  float xa[4], pa[4] = {0.f, 0.f, 0.f, 0.f};
  *(float4*)xa = ((const float4*)(X + (size_t)row * kD))[i];
  if (hp) *(float4*)pa = ((const float4*)(X + (size_t)(row - 1) * kD))[i];
  float s0 = xa[0] + xa[1] + xa[2] + xa[3];
  float q0 = xa[0] * xa[0] + xa[1] * xa[1] + xa[2] * xa[2] + xa[3] * xa[3];
  float s1 = pa[0] + pa[1] + pa[2] + pa[3];
  float q1 = pa[0] * pa[0] + pa[1] * pa[1] + pa[2] * pa[2] + pa[3] * pa[3];
#pragma unroll
  for (int off = 32; off > 0; off >>= 1) {
    s0 += __shfl_xor(s0, off); q0 += __shfl_xor(q0, off);
    s1 += __shfl_xor(s1, off); q1 += __shfl_xor(q1, off);
  }
  __shared__ float red[4][4];
  const int wid = i >> 6, lane = i & 63;
  if (lane == 0) { red[wid][0] = s0; red[wid][1] = q0; red[wid][2] = s1; red[wid][3] = q1; }
  __syncthreads();
  s0 = red[0][0] + red[1][0] + red[2][0] + red[3][0];
  q0 = red[0][1] + red[1][1] + red[2][1] + red[3][1];
  s1 = red[0][2] + red[1][2] + red[2][2] + red[3][2];
  q1 = red[0][3] + red[1][3] + red[2][3] + red[3][3];
  const float m0 = s0 * (1.f / kD);
  const float r0 = rsqrtf(fmaxf(q0 * (1.f / kD) - m0 * m0, 0.f) + 1e-5f);
  const float m1 = s1 * (1.f / kD);
  const float r1 = rsqrtf(fmaxf(q1 * (1.f / kD) - m1 * m1, 0.f) + 1e-5f);
  float ga[4], ba[4], ka[4], va[4], ra[4];
  *(float4*)ga = ((const float4*)g)[i];
  *(float4*)ba = ((const float4*)be)[i];
  *(float4*)ka = ((const float4*)mk)[i];
  *(float4*)va = ((const float4*)mv)[i];
  *(float4*)ra = ((const float4*)mr)[i];
  ushort4 uk, uv, ur;
  unsigned short* pk = (unsigned short*)&uk;
  unsigned short* pv = (unsigned short*)&uv;
  unsigned short* pr = (unsigned short*)&ur;
#pragma unroll
  for (int c = 0; c < 4; ++c) {
    float xn = (xa[c] - m0) * r0 * ga[c] + ba[c];
    float xp = hp ? (pa[c] - m1) * r1 * ga[c] + ba[c] : 0.f;   // shift: row 0 -> zeros
    pk[c] = f2bf(xn * ka[c] + xp * (1.f - ka[c]));
    pv[c] = f2bf(xn * va[c] + xp * (1.f - va[c]));
    pr[c] = f2bf(xn * ra[c] + xp * (1.f - ra[c]));
  }
  ((ushort4*)(ok + (size_t)row * kD))[i] = uk;
  ((ushort4*)(ov + (size_t)row * kD))[i] = uv;
  ((ushort4*)(orr + (size_t)row * kD))[i] = ur;
}

// -------- fused LN(+stats)+shift for channel mix: ymix = 0.5(yn+yp), ynb = yn --------
__global__ __launch_bounds__(256) void k_ln2f(
    const float* __restrict__ X, const float* __restrict__ g, const float* __restrict__ be,
    bf16_t* __restrict__ om, bf16_t* __restrict__ on) {
  const int row = blockIdx.x;
  const int l = row & (kL - 1);
  const int i = threadIdx.x;
  const bool hp = (l != 0);
  float xa[4], pa[4] = {0.f, 0.f, 0.f, 0.f};
  *(float4*)xa = ((const float4*)(X + (size_t)row * kD))[i];
  if (hp) *(float4*)pa = ((const float4*)(X + (size_t)(row - 1) * kD))[i];
  float s0 = xa[0] + xa[1] + xa[2] + xa[3];
  float q0 = xa[0] * xa[0] + xa[1] * xa[1] + xa[2] * xa[2] + xa[3] * xa[3];
  float s1 = pa[0] + pa[1] + pa[2] + pa[3];
  float q1 = pa[0] * pa[0] + pa[1] * pa[1] + pa[2] * pa[2] + pa[3] * pa[3];
#pragma unroll
  for (int off = 32; off > 0; off >>= 1) {
    s0 += __shfl_xor(s0, off); q0 += __shfl_xor(q0, off);
    s1 += __shfl_xor(s1, off); q1 += __shfl_xor(q1, off);
  }
  __shared__ float red[4][4];
  const int wid = i >> 6, lane = i & 63;
  if (lane == 0) { red[wid][0] = s0; red[wid][1] = q0; red[wid][2] = s1; red[wid][3] = q1; }
  __syncthreads();
  s0 = red[0][0] + red[1][0] + red[2][0] + red[3][0];
  q0 = red[0][1] + red[1][1] + red[2][1] + red[3][1];
  s1 = red[0][2] + red[1][2] + red[2][2] + red[3][2];
  q1 = red[0][3] + red[1][3] + red[2][3] + red[3][3];
  const float m0 = s0 * (1.f / kD);
  const float r0 = rsqrtf(fmaxf(q0 * (1.f / kD) - m0 * m0, 0.f) + 1e-5f);
  const float m1 = s1 * (1.f / kD);
  const float r1 = rsqrtf(fmaxf(q1 * (1.f / kD) - m1 * m1, 0.f) + 1e-5f);
  float ga[4], ba[4];
  *(float4*)ga = ((const float4*)g)[i];
  *(float4*)ba = ((const float4*)be)[i];
  ushort4 um, un;
  unsigned short* qm = (unsigned short*)&um;
  unsigned short* qn = (unsigned short*)&un;
#pragma unroll
  for (int c = 0; c < 4; ++c) {
    float yn = (xa[c] - m0) * r0 * ga[c] + ba[c];
    float yp = hp ? (pa[c] - m1) * r1 * ga[c] + ba[c] : 0.f;
    qm[c] = f2bf(0.5f * (yn + yp));
    qn[c] = f2bf(yn);
  }
  ((ushort4*)(om + (size_t)row * kD))[i] = um;
  ((ushort4*)(on + (size_t)row * kD))[i] = un;
}

// ===================== WKV: segmented parallel scan over L =====================
__global__ __launch_bounds__(256) void k_wkv_seg(
    const unsigned short* __restrict__ kq, const unsigned short* __restrict__ vq,
    const float* __restrict__ td, const float* __restrict__ tf,
    float* __restrict__ segA, float* __restrict__ segB) {
  const int d = blockIdx.x * 256 + threadIdx.x;
  const int b = blockIdx.y;
  const int s = blockIdx.z;
  const float ew = __expf(-__expf(td[d]));
  const float uu = (s == 0) ? tf[d] : 0.f;
  const size_t base = ((size_t)b * kL + (size_t)s * kP) * kD + d;
  float a = 0.f, bb = 0.f;
  unsigned short kA[16], vA[16], kB[16], vB[16];
  auto pref = [&](unsigned short* ka, unsigned short* va, int c) {
    const size_t o0 = base + (size_t)c * 16 * kD;
#pragma unroll
    for (int j = 0; j < 16; ++j) {
      ka[j] = kq[o0 + (size_t)j * kD];
      va[j] = vq[o0 + (size_t)j * kD];
    }
  };
  auto comp = [&](const unsigned short* ka, const unsigned short* va, int c) {
#pragma unroll
    for (int j = 0; j < 16; ++j) {
      float kf = bf2f(ka[j]);
      if (s == 0 && c == 0 && j == 0) kf += uu;    // t==0: exp(u + k0)
      float ek = __expf(kf);
      a = ew * a + ek * bf2f(va[j]);
      bb = ew * bb + ek;
    }
  };
  pref(kA, vA, 0);
  pref(kB, vB, 1); comp(kA, vA, 0);
  pref(kA, vA, 2); comp(kB, vB, 1);
  pref(kB, vB, 3); comp(kA, vA, 2);
  comp(kB, vB, 3);
  const size_t sidx = ((size_t)b * kSeg + s) * kD + d;
  segA[sidx] = a;
  segB[sidx] = bb;
}

__global__ __launch_bounds__(256) void k_wkv_carry(
    const float* __restrict__ td,
    const float* __restrict__ segA, const float* __restrict__ segB,
    float* __restrict__ carA, float* __restrict__ carB) {
  const int d = blockIdx.x * 256 + threadIdx.x;
  const int b = blockIdx.y;
  const float ew = __expf(-__expf(td[d]));
  float ewP = ew;
#pragma unroll
  for (int i = 0; i < 6; ++i) ewP *= ewP;          // ew^64
  float ca = 0.f, cb = 0.f;
#pragma unroll 4
  for (int s = 0; s < kSeg; ++s) {
    const size_t idx = ((size_t)b * kSeg + s) * kD + d;
    carA[idx] = ca;
    carB[idx] = cb;
    ca = ewP * ca + segA[idx];
    cb = ewP * cb + segB[idx];
  }
}

__global__ __launch_bounds__(256) void k_wkv_out(
    const unsigned short* __restrict__ kq, const unsigned short* __restrict__ vq,
    const unsigned short* __restrict__ rq, const float* __restrict__ td,
    const float* __restrict__ tf, const float* __restrict__ carA,
    const float* __restrict__ carB, unsigned short* __restrict__ out) {
  const int d = blockIdx.x * 256 + threadIdx.x;
  const int b = blockIdx.y;
  const int s = blockIdx.z;
  const float ew = __expf(-__expf(td[d]));
  const float uu = (s == 0) ? tf[d] : 0.f;
  const size_t base = ((size_t)b * kL + (size_t)s * kP) * kD + d;
  const size_t sidx = ((size_t)b * kSeg + s) * kD + d;
  float a = carA[sidx], bb = carB[sidx];
  unsigned short kA[16], vA[16], rA[16], kB[16], vB[16], rB[16];
  auto pref = [&](unsigned short* ka, unsigned short* va, unsigned short* ra, int c) {
    const size_t o0 = base + (size_t)c * 16 * kD;
#pragma unroll
    for (int j = 0; j < 16; ++j) {
      ka[j] = kq[o0 + (size_t)j * kD];
      va[j] = vq[o0 + (size_t)j * kD];
      ra[j] = rq[o0 + (size_t)j * kD];
    }
  };
  auto comp = [&](const unsigned short* ka, const unsigned short* va,
                  const unsigned short* ra, int c) {
    const size_t o0 = base + (size_t)c * 16 * kD;
#pragma unroll
    for (int j = 0; j < 16; ++j) {
      float kf = bf2f(ka[j]);
      if (s == 0 && c == 0 && j == 0) kf += uu;
      float ek = __expf(kf);
      a = ew * a + ek * bf2f(va[j]);
      bb = ew * bb + ek;
      float y = a / (bb + 1e-8f);
      float sr = 1.f / (1.f + __expf(-bf2f(ra[j])));
      out[o0 + (size_t)j * kD] = f2bf(sr * y);
    }
  };
  pref(kA, vA, rA, 0);
  pref(kB, vB, rB, 1); comp(kA, vA, rA, 0);
  pref(kA, vA, rA, 2); comp(kB, vB, rB, 1);
  pref(kB, vB, rB, 3); comp(kA, vA, rA, 2);
  comp(kB, vB, rB, 3);
}

// ====== bf16 MFMA GEMM: BM=BN=256 BK=64, 8 waves of 128x64; A via LDS, B blocked-direct ======
// B in blocked layout Wb[K/8][ldb][8]: one frag load = 16 lanes x 16B CONTIGUOUS
// (4x256B segments) -- fixes R10's 64-cacheline-per-instr disaster. Two static B
// register sets (bA even tiles / bB odd tiles, rule #20), loaded one full tile
// before their exact vmcnt(0) drain. A staged to LDS (dbuf 2x32KB, T2 swizzle,
// gld16). LDS/tile: 128KB reads + 32KB writes (~1300-1750cyc) < MFMA (2065cyc).
// Sync: one barrier + lgkm(0) + vmcnt(0) per tile; prologue exact-drain (R9 fix).
template <int EPI>
__global__ __launch_bounds__(512, 2) void gemmB(
    const bf16_t* __restrict__ A0, long strA, int lda,
    const bf16_t* __restrict__ Bblk0, long strB, int ldb,   // blocked [K/8][ldb][8]
    bf16_t* __restrict__ Cb0, float* __restrict__ Cf, long strC,
    int N, int K, int nbx,
    const float* __restrict__ addf, const bf16_t* __restrict__ mulb) {
  __shared__ __align__(16) char lds[65536];   // 2 x A[256][64]bf16
  const int z = blockIdx.z;
  const bf16_t* A = A0 + (size_t)z * strA;
  const bf16_t* Bblk = Bblk0 + (size_t)z * strB;
  const int nwg = gridDim.x;
  const int wg = (blockIdx.x & 7) * (nwg >> 3) + (blockIdx.x >> 3);
  const int by = wg / nbx, bx = wg - by * nbx;
  const long brow = (long)by * 256;
  const long bcol = (long)bx * 256;
  const int tid = threadIdx.x;
  const int lane = tid & 63;
  const int wid = tid >> 6;
  const int wr = wid >> 2, wc = wid & 3;   // 2 x 4 waves, each owns 128x64 out

  f32x4 acc[8][4] = {};

  // ---- A staging: thread covers 16B at (row q*64 + tid>>3, slot (tid&7)*16)
  const int trow = tid >> 3;
  const int scol = ((tid & 7) * 16) ^ ((trow & 7) << 4);   // pre-swizzled source col
  const char* Ag = (const char*)(A + (brow + trow) * (size_t)lda) + scol;
  const long rsA = 64L * lda * 2;

#define STAGE_A(kt, p)                                 \
  {                                                    \
    const long kb = (long)(kt) * 128;                  \
    char* Ld = lds + (p) * 32768 + tid * 16;           \
    gld16(Ag + kb, Ld);                                \
    gld16(Ag + kb + rsA, Ld + 8192);                   \
    gld16(Ag + kb + 2 * rsA, Ld + 16384);              \
    gld16(Ag + kb + 3 * rsA, Ld + 24576);              \
  }

  // ---- A fragment reads (swizzled): row r, logical byte-col c -> c ^ ((r&7)<<4)
  const int l16 = lane & 15, kq = lane >> 4;
  const int swz = (l16 & 7) << 4;
  const int oS0 = (kq * 16) ^ swz;          // K-slice 0 (k 0..31)
  const int oS1 = (64 + kq * 16) ^ swz;     // K-slice 1 (k 32..63)
  const int ArowOff = (wr * 128 + l16) * 128;

  // ---- B blocked addressing: addr(kt,sl,n) = ((kt*8+sl*4+kq)*ldb + bcol+wc*64+n*16+l16)*16B
  const char* Bb = (const char*)Bblk + ((size_t)kq * ldb + (size_t)(bcol + wc * 64 + l16)) * 16;
  const size_t tstr = (size_t)ldb * 128;    // +1 K-tile  (8 k-octets)
  const size_t sstr = (size_t)ldb * 64;     // +1 K-slice (4 k-octets)

  bf16x8 aF[4], bA[8], bB[8];
  const int NT = K >> 6;

#define BLOAD(dst, kt) { const char* bp = Bb + (size_t)(kt) * tstr;           \
  _Pragma("unroll") for (int n = 0; n < 4; ++n) {                             \
    dst[n] = *(const bf16x8*)(bp + n * 256);                                  \
    dst[4 + n] = *(const bf16x8*)(bp + sstr + n * 256); } }

  // one C-quadrant (m-half MB x K-slice OS) against B set BS[B0..B0+3]
#define QUAD(MB, OS, BS, B0)                                                  \
  _Pragma("unroll") for (int i = 0; i < 4; ++i)                               \
    aF[i] = *(const bf16x8*)(Ap + ((MB) * 4 + i) * 2048 + (OS));              \
  __builtin_amdgcn_s_setprio(1);                                              \
  _Pragma("unroll") for (int i = 0; i < 4; ++i)                               \
    _Pragma("unroll") for (int n = 0; n < 4; ++n)                             \
      acc[(MB) * 4 + i][n] = __builtin_amdgcn_mfma_f32_16x16x32_bf16(         \
          aF[i], BS[(B0) + n], acc[(MB) * 4 + i][n], 0, 0, 0);                \
  __builtin_amdgcn_s_setprio(0);

  // prologue: B(0) + A tiles 0,1; exact drain (order-independent)
  BLOAD(bA, 0)
  STAGE_A(0, 0) STAGE_A(1, 1)
  asm volatile("s_waitcnt vmcnt(0)" ::: "memory");
  __builtin_amdgcn_s_barrier();

  for (int t = 0; t < NT; t += 2) {
    {  // even tile t (LDS buf 0, B set bA)
      const char* Ap = lds + ArowOff;
      if (t + 1 < NT) BLOAD(bB, t + 1)
      QUAD(0, oS0, bA, 0) QUAD(1, oS0, bA, 0) QUAD(0, oS1, bA, 4) QUAD(1, oS1, bA, 4)
      asm volatile("s_waitcnt lgkmcnt(0)" ::: "memory");   // my reads of buf0 done
      asm volatile("s_waitcnt vmcnt(0)" ::: "memory");     // STAGE_A(t+1) + bB landed
      __builtin_amdgcn_s_barrier();
      if (t + 2 < NT) { STAGE_A(t + 2, 0) BLOAD(bA, t + 2) }
    }
    {  // odd tile t+1 (LDS buf 1, B set bB) -- NT is always even (16 or 32)
      const char* Ap = lds + 32768 + ArowOff;
      QUAD(0, oS0, bB, 0) QUAD(1, oS0, bB, 0) QUAD(0, oS1, bB, 4) QUAD(1, oS1, bB, 4)
      asm volatile("s_waitcnt lgkmcnt(0)" ::: "memory");
      asm volatile("s_waitcnt vmcnt(0)" ::: "memory");     // STAGE_A(t+2) + bA landed
      __builtin_amdgcn_s_barrier();
      if (t + 3 < NT) STAGE_A(t + 3, 1)
    }
  }
#undef STAGE_A
#undef BLOAD
#undef QUAD

  bf16_t* Cb = Cb0 + (size_t)z * strC;
  const long orow = brow + wr * 128 + (lane >> 4) * 4;  // C/D: col=lane&15, row=(lane>>4)*4+reg
  const long ocol = bcol + wc * 64 + l16;
#pragma unroll
  for (int m = 0; m < 8; ++m) {
#pragma unroll
    for (int reg = 0; reg < 4; ++reg) {
      const long r = orow + m * 16 + reg;
#pragma unroll
      for (int n = 0; n < 4; ++n) {
        const size_t idx = (size_t)r * N + ocol + n * 16;
        const float v = acc[m][n][reg];
        if constexpr (EPI == 0) {
          Cb[idx] = __float2bfloat16(v);
        } else if constexpr (EPI == 1) {
          Cf[idx] = addf[idx] + v;
        } else if constexpr (EPI == 2) {
          float u = v > 0.f ? v : 0.f;
          Cb[idx] = __float2bfloat16(u * u);
        } else if constexpr (EPI == 3) {
          Cb[idx] = __float2bfloat16(1.f / (1.f + __expf(-v)));
        } else if constexpr (EPI == 4) {
          Cf[idx] = v;
        } else {
          Cf[idx] = addf[idx] + __bfloat162float(mulb[idx]) * (Cf[idx] + v);
        }
      }
    }
  }
}

extern "C" void kernel_launch(void* const* d_in, const int* in_sizes, int n_in,
                              void* d_out, int out_size, void* d_ws, size_t ws_size,
                              hipStream_t stream) {
  const float* x    = (const float*)d_in[0];
  const float* ln1g = (const float*)d_in[1];
  const float* ln1b = (const float*)d_in[2];
  const float* Wk   = (const float*)d_in[3];
  const float* Wv   = (const float*)d_in[4];
  const float* Wr   = (const float*)d_in[5];
  const float* Wo   = (const float*)d_in[6];
  const float* td   = (const float*)d_in[7];
  const float* tf   = (const float*)d_in[8];
  const float* mk   = (const float*)d_in[9];
  const float* mv   = (const float*)d_in[10];
  const float* mr   = (const float*)d_in[11];
  const float* ln2g = (const float*)d_in[12];
  const float* ln2b = (const float*)d_in[13];
  const float* Wfk  = (const float*)d_in[14];
  const float* Wfv  = (const float*)d_in[15];
  const float* Wfr  = (const float*)d_in[16];

  char* ws = (char*)d_ws;
  const size_t MB = 1ull << 20;
  bf16_t* WkB  = (bf16_t*)(ws + 0 * MB);
  bf16_t* WvB  = (bf16_t*)(ws + 2 * MB);
  bf16_t* WrB  = (bf16_t*)(ws + 4 * MB);
  bf16_t* WoB  = (bf16_t*)(ws + 6 * MB);
  bf16_t* WfkB = (bf16_t*)(ws + 8 * MB);    // [128][4096][8]
  bf16_t* WfvB = (bf16_t*)(ws + 16 * MB);   // [512][1024][8]
  bf16_t* WfrB = (bf16_t*)(ws + 24 * MB);
  bf16_t* xk   = (bf16_t*)(ws + 28 * MB);
  bf16_t* xv   = (bf16_t*)(ws + 60 * MB);
  bf16_t* xr   = (bf16_t*)(ws + 92 * MB);
  bf16_t* kbuf = (bf16_t*)(ws + 124 * MB);
  bf16_t* vbuf = (bf16_t*)(ws + 156 * MB);
  bf16_t* rbuf = (bf16_t*)(ws + 188 * MB);
  float*  segA = (float*)(ws + 60 * MB);
  float*  segB = (float*)(ws + 61 * MB);
  float*  carA = (float*)(ws + 62 * MB);
  float*  carB = (float*)(ws + 63 * MB);
  bf16_t* rwkv = (bf16_t*)(ws + 92 * MB);
  float*  x1   = (float*)(ws + 28 * MB);    // f32 64 MB
  bf16_t* rr   = (bf16_t*)(ws + 92 * MB);
  bf16_t* ynb  = (bf16_t*)(ws + 124 * MB);
  bf16_t* kk   = (bf16_t*)(ws + 124 * MB);  // [16384][2048] bf16 = 64 MB
  bf16_t* ymix = (bf16_t*)(ws + 188 * MB);
  float*  out  = (float*)d_out;
  const long sX = (long)kM * kD;            // 16777216 elems
  const long sW = (long)kD * kD;            // 1048576 elems

  dim3 blk(256), blkg(512);
  // weights -> blocked bf16 [K/8][C][8]
  k_block8<<<dim3(4, 128), blk, 0, stream>>>(Wk, WkB, 1024);
  k_block8<<<dim3(4, 128), blk, 0, stream>>>(Wv, WvB, 1024);
  k_block8<<<dim3(4, 128), blk, 0, stream>>>(Wr, WrB, 1024);
  k_block8<<<dim3(4, 128), blk, 0, stream>>>(Wo, WoB, 1024);
  k_block8<<<dim3(16, 128), blk, 0, stream>>>(Wfk, WfkB, 4096);
  k_block8<<<dim3(4, 512), blk, 0, stream>>>(Wfv, WfvB, 1024);
  k_block8<<<dim3(4, 128), blk, 0, stream>>>(Wfr, WfrB, 1024);

  // ---- time mixing ----
  k_ln1f<<<kM, blk, 0, stream>>>(x, ln1g, ln1b, mk, mv, mr, xk, xv, xr);
  gemmB<0><<<dim3(256, 1, 3), blkg, 0, stream>>>(xk, sX, 1024, WkB, sW, 1024,
      kbuf, nullptr, sX, 1024, 1024, 4, nullptr, nullptr);
  k_wkv_seg<<<dim3(4, 8, kSeg), blk, 0, stream>>>((const unsigned short*)kbuf,
      (const unsigned short*)vbuf, td, tf, segA, segB);
  k_wkv_carry<<<dim3(4, 8), blk, 0, stream>>>(td, segA, segB, carA, carB);
  k_wkv_out<<<dim3(4, 8, kSeg), blk, 0, stream>>>((const unsigned short*)kbuf,
      (const unsigned short*)vbuf, (const unsigned short*)rbuf, td, tf, carA, carB,
      (unsigned short*)rwkv);
  gemmB<1><<<256, blkg, 0, stream>>>(rwkv, 0, 1024, WoB, 0, 1024,
      nullptr, x1, 0, 1024, 1024, 4, x, nullptr);

  // ---- channel mixing ----
  k_ln2f<<<kM, blk, 0, stream>>>(x1, ln2g, ln2b, ymix, ynb);
  gemmB<3><<<256, blkg, 0, stream>>>(ynb, 0, 1024, WfrB, 0, 1024,
      rr, nullptr, 0, 1024, 1024, 4, nullptr, nullptr);
  // hidden dim in 2 chunks of 2048: kk = relu(ymix@Wfk[:,c])^2; out (+)= kk@Wfv[c,:]
  for (int c = 0; c < 2; ++c) {
    gemmB<2><<<512, blkg, 0, stream>>>(ymix, 0, 1024, WfkB + (size_t)c * 2048 * 8, 0, 4096,
        kk, nullptr, 0, 2048, 1024, 8, nullptr, nullptr);
    if (c == 0)
      gemmB<4><<<256, blkg, 0, stream>>>(kk, 0, 2048, WfvB, 0, 1024,
          nullptr, out, 0, 1024, 2048, 4, nullptr, nullptr);
    else
      gemmB<6><<<256, blkg, 0, stream>>>(kk, 0, 2048, WfvB + (size_t)256 * 1024 * 8, 0, 1024,
          nullptr, out, 0, 1024, 2048, 4, x1, rr);
  }
}

// Round 12
// 675.531 us; speedup vs baseline: 1.6694x; 1.6694x over previous
//
#include <hip/hip_runtime.h>
#include <hip/hip_bf16.h>
#include <stdint.h>

typedef __hip_bfloat16 bf16_t;
typedef __attribute__((ext_vector_type(8))) short bf16x8;     // 8 bf16 = 4 VGPR
typedef __attribute__((ext_vector_type(16))) float f32x16;    // 32x32 MFMA acc

#define DEV static __device__ __forceinline__

constexpr int kBB = 8, kL = 2048, kD = 1024;
constexpr int kM = kBB * kL;   // 16384 rows
constexpr int kSeg = 32, kP = 64;   // WKV: 32 segments x 64 steps

DEV float bf2f(unsigned short u) { return __uint_as_float((unsigned)u << 16); }
DEV unsigned short f2bf(float f) {
  unsigned u = __float_as_uint(f);
  return (unsigned short)((u + 0x7fffu + ((u >> 16) & 1u)) >> 16);  // RNE
}

// async global->LDS, 16B per lane. LDS dest is wave-uniform-base + lane*16.
DEV void gld16(const void* g, void* l) {
  const __attribute__((address_space(1))) unsigned* gp =
      (const __attribute__((address_space(1))) unsigned*)(uintptr_t)g;
  __attribute__((address_space(3))) unsigned* lp =
      (__attribute__((address_space(3))) unsigned*)(unsigned)(uintptr_t)l;
  __builtin_amdgcn_global_load_lds(gp, lp, 16, 0, 0);
}

// ---------------- weight transpose + cast: W[R][C] f32 -> Wt[C][R] bf16 ---------------
__global__ __launch_bounds__(256) void k_transpose_cast(
    const float* __restrict__ W, bf16_t* __restrict__ Wt, int R, int C) {
  __shared__ float tile[32][33];
  const int bx = blockIdx.x * 32;           // C-dim base
  const int by = blockIdx.y * 32;           // R-dim base
  const int tx = threadIdx.x & 31, ty = threadIdx.x >> 5;  // 32 x 8
#pragma unroll
  for (int i = 0; i < 32; i += 8)
    tile[ty + i][tx] = W[(size_t)(by + ty + i) * C + (bx + tx)];
  __syncthreads();
#pragma unroll
  for (int i = 0; i < 32; i += 8)
    Wt[(size_t)(bx + ty + i) * R + (by + tx)] = __float2bfloat16(tile[tx][ty + i]);
}

// -------- fused LN(+stats)+shift+time-mix -> xk/xv/xr (bf16); one block per row --------
__global__ __launch_bounds__(256) void k_ln1f(
    const float* __restrict__ X, const float* __restrict__ g, const float* __restrict__ be,
    const float* __restrict__ mk, const float* __restrict__ mv, const float* __restrict__ mr,
    bf16_t* __restrict__ ok, bf16_t* __restrict__ ov, bf16_t* __restrict__ orr) {
  const int row = blockIdx.x;
  const int l = row & (kL - 1);
  const int i = threadIdx.x;                 // 4 floats per thread
  const bool hp = (l != 0);
  float xa[4], pa[4] = {0.f, 0.f, 0.f, 0.f};
  *(float4*)xa = ((const float4*)(X + (size_t)row * kD))[i];
  if (hp) *(float4*)pa = ((const float4*)(X + (size_t)(row - 1) * kD))[i];
  float s0 = xa[0] + xa[1] + xa[2] + xa[3];
  float q0 = xa[0] * xa[0] + xa[1] * xa[1] + xa[2] * xa[2] + xa[3] * xa[3];
  float s1 = pa[0] + pa[1] + pa[2] + pa[3];
  float q1 = pa[0] * pa[0] + pa[1] * pa[1] + pa[2] * pa[2] + pa[3] * pa[3];
#pragma unroll
  for (int off = 32; off > 0; off >>= 1) {
    s0 += __shfl_xor(s0, off); q0 += __shfl_xor(q0, off);
    s1 += __shfl_xor(s1, off); q1 += __shfl_xor(q1, off);
  }
  __shared__ float red[4][4];
  const int wid = i >> 6, lane = i & 63;
  if (lane == 0) { red[wid][0] = s0; red[wid][1] = q0; red[wid][2] = s1; red[wid][3] = q1; }
  __syncthreads();
  s0 = red[0][0] + red[1][0] + red[2][0] + red[3][0];
  q0 = red[0][1] + red[1][1] + red[2][1] + red[3][1];
  s1 = red[0][2] + red[1][2] + red[2][2] + red[3][2];
  q1 = red[0][3] + red[1][3] + red[2][3] + red[3][3];
  const float m0 = s0 * (1.f / kD);
  const float r0 = rsqrtf(fmaxf(q0 * (1.f / kD) - m0 * m0, 0.f) + 1e-5f);
  const float m1 = s1 * (1.f / kD);
  const float r1 = rsqrtf(fmaxf(q1 * (1.f / kD) - m1 * m1, 0.f) + 1e-5f);
  float ga[4], ba[4], ka[4], va[4], ra[4];
  *(float4*)ga = ((const float4*)g)[i];
  *(float4*)ba = ((const float4*)be)[i];
  *(float4*)ka = ((const float4*)mk)[i];
  *(float4*)va = ((const float4*)mv)[i];
  *(float4*)ra = ((const float4*)mr)[i];
  ushort4 uk, uv, ur;
  unsigned short* pk = (unsigned short*)&uk;
  unsigned short* pv = (unsigned short*)&uv;
  unsigned short* pr = (unsigned short*)&ur;
#pragma unroll
  for (int c = 0; c < 4; ++c) {
    float xn = (xa[c] - m0) * r0 * ga[c] + ba[c];
    float xp = hp ? (pa[c] - m1) * r1 * ga[c] + ba[c] : 0.f;   // shift: row 0 -> zeros
    pk[c] = f2bf(xn * ka[c] + xp * (1.f - ka[c]));
    pv[c] = f2bf(xn * va[c] + xp * (1.f - va[c]));
    pr[c] = f2bf(xn * ra[c] + xp * (1.f - ra[c]));
  }
  ((ushort4*)(ok + (size_t)row * kD))[i] = uk;
  ((ushort4*)(ov + (size_t)row * kD))[i] = uv;
  ((ushort4*)(orr + (size_t)row * kD))[i] = ur;
}

// ---- fused LN(+stats)+shift for channel mix, bf16 input x1: ymix=0.5(yn+yp), ynb=yn ----
__global__ __launch_bounds__(256) void k_ln2fb(
    const bf16_t* __restrict__ X, const float* __restrict__ g, const float* __restrict__ be,
    bf16_t* __restrict__ om, bf16_t* __restrict__ on) {
  const int row = blockIdx.x;
  const int l = row & (kL - 1);
  const int i = threadIdx.x;
  const bool hp = (l != 0);
  ushort4 xu = ((const ushort4*)(X + (size_t)row * kD))[i];
  ushort4 pu = make_ushort4(0, 0, 0, 0);
  if (hp) pu = ((const ushort4*)(X + (size_t)(row - 1) * kD))[i];
  float xa[4], pa[4];
  xa[0] = bf2f(xu.x); xa[1] = bf2f(xu.y); xa[2] = bf2f(xu.z); xa[3] = bf2f(xu.w);
  pa[0] = bf2f(pu.x); pa[1] = bf2f(pu.y); pa[2] = bf2f(pu.z); pa[3] = bf2f(pu.w);
  float s0 = xa[0] + xa[1] + xa[2] + xa[3];
  float q0 = xa[0] * xa[0] + xa[1] * xa[1] + xa[2] * xa[2] + xa[3] * xa[3];
  float s1 = pa[0] + pa[1] + pa[2] + pa[3];
  float q1 = pa[0] * pa[0] + pa[1] * pa[1] + pa[2] * pa[2] + pa[3] * pa[3];
#pragma unroll
  for (int off = 32; off > 0; off >>= 1) {
    s0 += __shfl_xor(s0, off); q0 += __shfl_xor(q0, off);
    s1 += __shfl_xor(s1, off); q1 += __shfl_xor(q1, off);
  }
  __shared__ float red[4][4];
  const int wid = i >> 6, lane = i & 63;
  if (lane == 0) { red[wid][0] = s0; red[wid][1] = q0; red[wid][2] = s1; red[wid][3] = q1; }
  __syncthreads();
  s0 = red[0][0] + red[1][0] + red[2][0] + red[3][0];
  q0 = red[0][1] + red[1][1] + red[2][1] + red[3][1];
  s1 = red[0][2] + red[1][2] + red[2][2] + red[3][2];
  q1 = red[0][3] + red[1][3] + red[2][3] + red[3][3];
  const float m0 = s0 * (1.f / kD);
  const float r0 = rsqrtf(fmaxf(q0 * (1.f / kD) - m0 * m0, 0.f) + 1e-5f);
  const float m1 = s1 * (1.f / kD);
  const float r1 = rsqrtf(fmaxf(q1 * (1.f / kD) - m1 * m1, 0.f) + 1e-5f);
  float ga[4], ba[4];
  *(float4*)ga = ((const float4*)g)[i];
  *(float4*)ba = ((const float4*)be)[i];
  ushort4 um, un;
  unsigned short* qm = (unsigned short*)&um;
  unsigned short* qn = (unsigned short*)&un;
#pragma unroll
  for (int c = 0; c < 4; ++c) {
    float yn = (xa[c] - m0) * r0 * ga[c] + ba[c];
    float yp = hp ? (pa[c] - m1) * r1 * ga[c] + ba[c] : 0.f;
    qm[c] = f2bf(0.5f * (yn + yp));
    qn[c] = f2bf(yn);
  }
  ((ushort4*)(om + (size_t)row * kD))[i] = um;
  ((ushort4*)(on + (size_t)row * kD))[i] = un;
}

// ===================== WKV: segmented parallel scan over L =====================
__global__ __launch_bounds__(256) void k_wkv_seg(
    const unsigned short* __restrict__ kq, const unsigned short* __restrict__ vq,
    const float* __restrict__ td, const float* __restrict__ tf,
    float* __restrict__ segA, float* __restrict__ segB) {
  const int d = blockIdx.x * 256 + threadIdx.x;
  const int b = blockIdx.y;
  const int s = blockIdx.z;
  const float ew = __expf(-__expf(td[d]));
  const float uu = (s == 0) ? tf[d] : 0.f;
  const size_t base = ((size_t)b * kL + (size_t)s * kP) * kD + d;
  float a = 0.f, bb = 0.f;
  unsigned short kA[16], vA[16], kB[16], vB[16];
  auto pref = [&](unsigned short* ka, unsigned short* va, int c) {
    const size_t o0 = base + (size_t)c * 16 * kD;
#pragma unroll
    for (int j = 0; j < 16; ++j) {
      ka[j] = kq[o0 + (size_t)j * kD];
      va[j] = vq[o0 + (size_t)j * kD];
    }
  };
  auto comp = [&](const unsigned short* ka, const unsigned short* va, int c) {
#pragma unroll
    for (int j = 0; j < 16; ++j) {
      float kf = bf2f(ka[j]);
      if (s == 0 && c == 0 && j == 0) kf += uu;    // t==0: exp(u + k0)
      float ek = __expf(kf);
      a = ew * a + ek * bf2f(va[j]);
      bb = ew * bb + ek;
    }
  };
  pref(kA, vA, 0);
  pref(kB, vB, 1); comp(kA, vA, 0);
  pref(kA, vA, 2); comp(kB, vB, 1);
  pref(kB, vB, 3); comp(kA, vA, 2);
  comp(kB, vB, 3);
  const size_t sidx = ((size_t)b * kSeg + s) * kD + d;
  segA[sidx] = a;
  segB[sidx] = bb;
}

__global__ __launch_bounds__(256) void k_wkv_carry(
    const float* __restrict__ td,
    const float* __restrict__ segA, const float* __restrict__ segB,
    float* __restrict__ carA, float* __restrict__ carB) {
  const int d = blockIdx.x * 256 + threadIdx.x;
  const int b = blockIdx.y;
  const float ew = __expf(-__expf(td[d]));
  float ewP = ew;
#pragma unroll
  for (int i = 0; i < 6; ++i) ewP *= ewP;          // ew^64
  float ca = 0.f, cb = 0.f;
#pragma unroll 4
  for (int s = 0; s < kSeg; ++s) {
    const size_t idx = ((size_t)b * kSeg + s) * kD + d;
    carA[idx] = ca;
    carB[idx] = cb;
    ca = ewP * ca + segA[idx];
    cb = ewP * cb + segB[idx];
  }
}

__global__ __launch_bounds__(256) void k_wkv_out(
    const unsigned short* __restrict__ kq, const unsigned short* __restrict__ vq,
    const unsigned short* __restrict__ rq, const float* __restrict__ td,
    const float* __restrict__ tf, const float* __restrict__ carA,
    const float* __restrict__ carB, unsigned short* __restrict__ out) {
  const int d = blockIdx.x * 256 + threadIdx.x;
  const int b = blockIdx.y;
  const int s = blockIdx.z;
  const float ew = __expf(-__expf(td[d]));
  const float uu = (s == 0) ? tf[d] : 0.f;
  const size_t base = ((size_t)b * kL + (size_t)s * kP) * kD + d;
  const size_t sidx = ((size_t)b * kSeg + s) * kD + d;
  float a = carA[sidx], bb = carB[sidx];
  unsigned short kA[16], vA[16], rA[16], kB[16], vB[16], rB[16];
  auto pref = [&](unsigned short* ka, unsigned short* va, unsigned short* ra, int c) {
    const size_t o0 = base + (size_t)c * 16 * kD;
#pragma unroll
    for (int j = 0; j < 16; ++j) {
      ka[j] = kq[o0 + (size_t)j * kD];
      va[j] = vq[o0 + (size_t)j * kD];
      ra[j] = rq[o0 + (size_t)j * kD];
    }
  };
  auto comp = [&](const unsigned short* ka, const unsigned short* va,
                  const unsigned short* ra, int c) {
    const size_t o0 = base + (size_t)c * 16 * kD;
#pragma unroll
    for (int j = 0; j < 16; ++j) {
      float kf = bf2f(ka[j]);
      if (s == 0 && c == 0 && j == 0) kf += uu;
      float ek = __expf(kf);
      a = ew * a + ek * bf2f(va[j]);
      bb = ew * bb + ek;
      float y = a / (bb + 1e-8f);
      float sr = 1.f / (1.f + __expf(-bf2f(ra[j])));
      out[o0 + (size_t)j * kD] = f2bf(sr * y);
    }
  };
  pref(kA, vA, rA, 0);
  pref(kB, vB, rB, 1); comp(kA, vA, rA, 0);
  pref(kA, vA, rA, 2); comp(kB, vB, rB, 1);
  pref(kB, vB, rB, 3); comp(kA, vA, rA, 2);
  comp(kB, vB, rB, 3);
}

// ====== bf16 MFMA GEMM: BM=BN=256 BK=64, 8 waves of 128x64, 32x32x16 MFMA ======
// R8's verified 2-phase skeleton (A+B via LDS, dbuf, one barrier + lgkm(0) +
// vmcnt(0) per tile, T1 bands, T2 swizzle, T5 setprio) with the MFMA shape
// switched to 32x32x16: ceiling 2495 vs 2176 TF (m119), half the instruction
// count, identical LDS bytes / read counts / register footprint.
// A-frag: row = wr*128 + mt*32 + (lane&31); 16B at kstep*32 + (lane>>5)*16.
// C/D (HW-verified m74/m101): col=lane&31, row=(reg&3)+8*(reg>>2)+4*(lane>>5).
// EPI: 0 bf16 store, 1 bf16 addf(f32)+acc [x1b], 2 relu(acc)^2, 3 sigmoid,
//      4 f32 store acc, 6 f32 addb(bf16) + mulb*(Cf+acc) [final combine]
template <int EPI>
__global__ __launch_bounds__(512, 2) void gemmT(
    const bf16_t* __restrict__ A0, long strA, int lda,
    const bf16_t* __restrict__ B0, long strB, int ldb,
    bf16_t* __restrict__ Cb0, float* __restrict__ Cf, long strC,
    int N, int K, int nbx,
    const float* __restrict__ addf, const bf16_t* __restrict__ addb,
    const bf16_t* __restrict__ mulb) {
  __shared__ __align__(16) char lds[131072];   // 2 x (A[256][64]bf16 @0 + B[256][64] @32768)
  const int z = blockIdx.z;
  const bf16_t* A = A0 + (size_t)z * strA;
  const bf16_t* Bt = B0 + (size_t)z * strB;
  const int nwg = gridDim.x;
  const int wg = (blockIdx.x & 7) * (nwg >> 3) + (blockIdx.x >> 3);
  const int by = wg / nbx, bx = wg - by * nbx;
  const long brow = (long)by * 256;
  const long bcol = (long)bx * 256;
  const int tid = threadIdx.x;
  const int lane = tid & 63;
  const int wid = tid >> 6;
  const int wr = wid >> 2, wc = wid & 3;   // 2 x 4 waves, each owns 128x64 out

  f32x16 acc[4][2] = {};                   // 4 m-tiles x 2 n-tiles of 32x32

  // staging: thread covers 16B at (row = q*64 + tid>>3, slot = (tid&7)*16)
  const int trow = tid >> 3;
  const int scol = ((tid & 7) * 16) ^ ((trow & 7) << 4);   // pre-swizzled source col
  const char* Ag = (const char*)(A + (brow + trow) * (size_t)lda) + scol;
  const char* Bg = (const char*)(Bt + (bcol + trow) * (size_t)ldb) + scol;
  const long rsA = 64L * lda * 2;
  const long rsB = 64L * ldb * 2;

#define STAGE(kt, p)                                   \
  {                                                    \
    const long kb = (long)(kt) * 128;                  \
    char* Ld = lds + (p) * 65536 + tid * 16;           \
    gld16(Ag + kb, Ld);                                \
    gld16(Ag + kb + rsA, Ld + 8192);                   \
    gld16(Ag + kb + 2 * rsA, Ld + 16384);              \
    gld16(Ag + kb + 3 * rsA, Ld + 24576);              \
    gld16(Bg + kb, Ld + 32768);                        \
    gld16(Bg + kb + rsB, Ld + 40960);                  \
    gld16(Bg + kb + 2 * rsB, Ld + 49152);              \
    gld16(Bg + kb + 3 * rsB, Ld + 57344);              \
  }

  // fragment reads (swizzled): row r, logical byte-col c -> c ^ ((r&7)<<4); r&7 = lane&7
  const int l31 = lane & 31;
  const int kh = lane >> 5;                 // k-half selector within 32B k-step extent
  const int swz = (lane & 7) << 4;
  const int o0 = (0 * 32 + kh * 16) ^ swz;  // k-step 0 (k 0..15)
  const int o1 = (1 * 32 + kh * 16) ^ swz;  // k-step 1
  const int o2 = (2 * 32 + kh * 16) ^ swz;  // k-step 2
  const int o3 = (3 * 32 + kh * 16) ^ swz;  // k-step 3
  const char* Arow = lds + (wr * 128 + l31) * 128;           // A m-tile mt: +mt*4096
  const char* Brow = lds + 32768 + (wc * 64 + l31) * 128;    // B n-tile nt: +nt*4096

  bf16x8 aE[8], bE[4], aO[8], bO[4];        // [mt*2+js] / [nt*2+js]
  const int NT = K >> 6;

  STAGE(0, 0) STAGE(1, 1)
  asm volatile("s_waitcnt vmcnt(8)" ::: "memory");   // STAGE(0) landed (intrinsics ordered)
  __builtin_amdgcn_s_barrier();
#pragma unroll
  for (int mt = 0; mt < 4; ++mt) {
    aE[mt * 2] = *(const bf16x8*)(Arow + mt * 4096 + o0);
    aE[mt * 2 + 1] = *(const bf16x8*)(Arow + mt * 4096 + o1);
  }
#pragma unroll
  for (int nt = 0; nt < 2; ++nt) {
    bE[nt * 2] = *(const bf16x8*)(Brow + nt * 4096 + o0);
    bE[nt * 2 + 1] = *(const bf16x8*)(Brow + nt * 4096 + o1);
  }

  for (int t = 0; t < NT; ++t) {
    const int p = t & 1;
    const char* Ap = Arow + p * 65536;
    const char* Bp = Brow + p * 65536;
    // issue reads of k-steps 2,3 (consumed by the NEXT cluster); pin above MFMA
#pragma unroll
    for (int mt = 0; mt < 4; ++mt) {
      aO[mt * 2] = *(const bf16x8*)(Ap + mt * 4096 + o2);
      aO[mt * 2 + 1] = *(const bf16x8*)(Ap + mt * 4096 + o3);
    }
#pragma unroll
    for (int nt = 0; nt < 2; ++nt) {
      bO[nt * 2] = *(const bf16x8*)(Bp + nt * 4096 + o2);
      bO[nt * 2 + 1] = *(const bf16x8*)(Bp + nt * 4096 + o3);
    }
    __builtin_amdgcn_sched_barrier(0);
    __builtin_amdgcn_s_setprio(1);
#pragma unroll
    for (int mt = 0; mt < 4; ++mt)
#pragma unroll
      for (int nt = 0; nt < 2; ++nt) {
        acc[mt][nt] = __builtin_amdgcn_mfma_f32_32x32x16_bf16(aE[mt * 2], bE[nt * 2], acc[mt][nt], 0, 0, 0);
        acc[mt][nt] = __builtin_amdgcn_mfma_f32_32x32x16_bf16(aE[mt * 2 + 1], bE[nt * 2 + 1], acc[mt][nt], 0, 0, 0);
      }
    __builtin_amdgcn_s_setprio(0);
    asm volatile("s_waitcnt lgkmcnt(0)" ::: "memory");   // my reads of buf p done
    asm volatile("s_waitcnt vmcnt(0)" ::: "memory");     // STAGE(t+1) landed (1 tile old)
    __builtin_amdgcn_s_barrier();                        // p free to overwrite; 1-p ready
    if (t + 2 < NT) STAGE(t + 2, p)
    if (t + 1 < NT) {
      const char* An = Arow + (1 - p) * 65536;
      const char* Bn = Brow + (1 - p) * 65536;
#pragma unroll
      for (int mt = 0; mt < 4; ++mt) {
        aE[mt * 2] = *(const bf16x8*)(An + mt * 4096 + o0);
        aE[mt * 2 + 1] = *(const bf16x8*)(An + mt * 4096 + o1);
      }
#pragma unroll
      for (int nt = 0; nt < 2; ++nt) {
        bE[nt * 2] = *(const bf16x8*)(Bn + nt * 4096 + o0);
        bE[nt * 2 + 1] = *(const bf16x8*)(Bn + nt * 4096 + o1);
      }
    }
    __builtin_amdgcn_sched_barrier(0);
    __builtin_amdgcn_s_setprio(1);
#pragma unroll
    for (int mt = 0; mt < 4; ++mt)
#pragma unroll
      for (int nt = 0; nt < 2; ++nt) {
        acc[mt][nt] = __builtin_amdgcn_mfma_f32_32x32x16_bf16(aO[mt * 2], bO[nt * 2], acc[mt][nt], 0, 0, 0);
        acc[mt][nt] = __builtin_amdgcn_mfma_f32_32x32x16_bf16(aO[mt * 2 + 1], bO[nt * 2 + 1], acc[mt][nt], 0, 0, 0);
      }
    __builtin_amdgcn_s_setprio(0);
  }
#undef STAGE

  bf16_t* Cb = Cb0 + (size_t)z * strC;
  // C/D: col = lane&31, row = (reg&3) + 8*(reg>>2) + 4*(lane>>5)
  const long orow = brow + wr * 128 + 4 * kh;
  const long ocol = bcol + wc * 64 + l31;
#pragma unroll
  for (int mt = 0; mt < 4; ++mt) {
#pragma unroll
    for (int reg = 0; reg < 16; ++reg) {
      const long r = orow + mt * 32 + (reg & 3) + 8 * (reg >> 2);
#pragma unroll
      for (int nt = 0; nt < 2; ++nt) {
        const size_t idx = (size_t)r * N + ocol + nt * 32;
        const float v = acc[mt][nt][reg];
        if constexpr (EPI == 0) {
          Cb[idx] = __float2bfloat16(v);
        } else if constexpr (EPI == 1) {
          Cb[idx] = __float2bfloat16(addf[idx] + v);
        } else if constexpr (EPI == 2) {
          float u = v > 0.f ? v : 0.f;
          Cb[idx] = __float2bfloat16(u * u);
        } else if constexpr (EPI == 3) {
          Cb[idx] = __float2bfloat16(1.f / (1.f + __expf(-v)));
        } else if constexpr (EPI == 4) {
          Cf[idx] = v;
        } else {
          Cf[idx] = __bfloat162float(addb[idx]) + __bfloat162float(mulb[idx]) * (Cf[idx] + v);
        }
      }
    }
  }
}

extern "C" void kernel_launch(void* const* d_in, const int* in_sizes, int n_in,
                              void* d_out, int out_size, void* d_ws, size_t ws_size,
                              hipStream_t stream) {
  const float* x    = (const float*)d_in[0];
  const float* ln1g = (const float*)d_in[1];
  const float* ln1b = (const float*)d_in[2];
  const float* Wk   = (const float*)d_in[3];
  const float* Wv   = (const float*)d_in[4];
  const float* Wr   = (const float*)d_in[5];
  const float* Wo   = (const float*)d_in[6];
  const float* td   = (const float*)d_in[7];
  const float* tf   = (const float*)d_in[8];
  const float* mk   = (const float*)d_in[9];
  const float* mv   = (const float*)d_in[10];
  const float* mr   = (const float*)d_in[11];
  const float* ln2g = (const float*)d_in[12];
  const float* ln2b = (const float*)d_in[13];
  const float* Wfk  = (const float*)d_in[14];
  const float* Wfv  = (const float*)d_in[15];
  const float* Wfr  = (const float*)d_in[16];

  char* ws = (char*)d_ws;
  const size_t MB = 1ull << 20;
  bf16_t* WkT  = (bf16_t*)(ws + 0 * MB);
  bf16_t* WvT  = (bf16_t*)(ws + 2 * MB);
  bf16_t* WrT  = (bf16_t*)(ws + 4 * MB);
  bf16_t* WoT  = (bf16_t*)(ws + 6 * MB);
  bf16_t* WfkT = (bf16_t*)(ws + 8 * MB);    // [4096][1024]
  bf16_t* WfvT = (bf16_t*)(ws + 16 * MB);   // [1024][4096]
  bf16_t* WfrT = (bf16_t*)(ws + 24 * MB);
  bf16_t* xk   = (bf16_t*)(ws + 28 * MB);
  bf16_t* xv   = (bf16_t*)(ws + 60 * MB);
  bf16_t* xr   = (bf16_t*)(ws + 92 * MB);
  bf16_t* kbuf = (bf16_t*)(ws + 124 * MB);
  bf16_t* vbuf = (bf16_t*)(ws + 156 * MB);
  bf16_t* rbuf = (bf16_t*)(ws + 188 * MB);
  float*  segA = (float*)(ws + 60 * MB);
  float*  segB = (float*)(ws + 61 * MB);
  float*  carA = (float*)(ws + 62 * MB);
  float*  carB = (float*)(ws + 63 * MB);
  bf16_t* rwkv = (bf16_t*)(ws + 92 * MB);
  bf16_t* x1b  = (bf16_t*)(ws + 28 * MB);   // bf16 residual, 32 MB
  bf16_t* rr   = (bf16_t*)(ws + 92 * MB);
  bf16_t* ynb  = (bf16_t*)(ws + 124 * MB);
  bf16_t* kk   = (bf16_t*)(ws + 124 * MB);  // [16384][2048] bf16 = 64 MB
  bf16_t* ymix = (bf16_t*)(ws + 188 * MB);
  float*  out  = (float*)d_out;
  const long sX = (long)kM * kD;            // 16777216 elems
  const long sW = (long)kD * kD;            // 1048576 elems

  dim3 blk(256), blkg(512);
  // weights -> bf16 B^T
  k_transpose_cast<<<dim3(32, 32), blk, 0, stream>>>(Wk, WkT, 1024, 1024);
  k_transpose_cast<<<dim3(32, 32), blk, 0, stream>>>(Wv, WvT, 1024, 1024);
  k_transpose_cast<<<dim3(32, 32), blk, 0, stream>>>(Wr, WrT, 1024, 1024);
  k_transpose_cast<<<dim3(32, 32), blk, 0, stream>>>(Wo, WoT, 1024, 1024);
  k_transpose_cast<<<dim3(128, 32), blk, 0, stream>>>(Wfk, WfkT, 1024, 4096);
  k_transpose_cast<<<dim3(32, 128), blk, 0, stream>>>(Wfv, WfvT, 4096, 1024);
  k_transpose_cast<<<dim3(32, 32), blk, 0, stream>>>(Wfr, WfrT, 1024, 1024);

  // ---- time mixing ----
  k_ln1f<<<kM, blk, 0, stream>>>(x, ln1g, ln1b, mk, mv, mr, xk, xv, xr);
  gemmT<0><<<dim3(256, 1, 3), blkg, 0, stream>>>(xk, sX, 1024, WkT, sW, 1024,
      kbuf, nullptr, sX, 1024, 1024, 4, nullptr, nullptr, nullptr);
  k_wkv_seg<<<dim3(4, 8, kSeg), blk, 0, stream>>>((const unsigned short*)kbuf,
      (const unsigned short*)vbuf, td, tf, segA, segB);
  k_wkv_carry<<<dim3(4, 8), blk, 0, stream>>>(td, segA, segB, carA, carB);
  k_wkv_out<<<dim3(4, 8, kSeg), blk, 0, stream>>>((const unsigned short*)kbuf,
      (const unsigned short*)vbuf, (const unsigned short*)rbuf, td, tf, carA, carB,
      (unsigned short*)rwkv);
  gemmT<1><<<256, blkg, 0, stream>>>(rwkv, 0, 1024, WoT, 0, 1024,
      x1b, nullptr, 0, 1024, 1024, 4, x, nullptr, nullptr);

  // ---- channel mixing ----
  k_ln2fb<<<kM, blk, 0, stream>>>(x1b, ln2g, ln2b, ymix, ynb);
  gemmT<3><<<256, blkg, 0, stream>>>(ynb, 0, 1024, WfrT, 0, 1024,
      rr, nullptr, 0, 1024, 1024, 4, nullptr, nullptr, nullptr);
  // hidden dim in 2 chunks of 2048: kk = relu(ymix@Wfk[:,c])^2; out (+)= kk@Wfv[c,:]
  for (int c = 0; c < 2; ++c) {
    gemmT<2><<<512, blkg, 0, stream>>>(ymix, 0, 1024, WfkT + (size_t)c * 2048 * 1024, 0, 1024,
        kk, nullptr, 0, 2048, 1024, 8, nullptr, nullptr, nullptr);
    if (c == 0)
      gemmT<4><<<256, blkg, 0, stream>>>(kk, 0, 2048, WfvT + 0, 0, 4096,
          nullptr, out, 0, 1024, 2048, 4, nullptr, nullptr, nullptr);
    else
      gemmT<6><<<256, blkg, 0, stream>>>(kk, 0, 2048, WfvT + 2048, 0, 4096,
          nullptr, out, 0, 1024, 2048, 4, nullptr, x1b, rr);
  }
}

// Round 13
// 629.225 us; speedup vs baseline: 1.7923x; 1.0736x over previous
//
#include <hip/hip_runtime.h>
#include <hip/hip_bf16.h>
#include <stdint.h>

typedef __hip_bfloat16 bf16_t;
typedef __attribute__((ext_vector_type(8))) short bf16x8;   // 8 bf16 = 4 VGPR
typedef __attribute__((ext_vector_type(4))) float f32x4;

#define DEV static __device__ __forceinline__

constexpr int kBB = 8, kL = 2048, kD = 1024;
constexpr int kM = kBB * kL;   // 16384 rows
constexpr int kSeg = 32, kP = 64;   // WKV: 32 segments x 64 steps

DEV float bf2f(unsigned short u) { return __uint_as_float((unsigned)u << 16); }
DEV unsigned short f2bf(float f) {
  unsigned u = __float_as_uint(f);
  return (unsigned short)((u + 0x7fffu + ((u >> 16) & 1u)) >> 16);  // RNE
}

// async global->LDS, 16B per lane. LDS dest is wave-uniform-base + lane*16.
DEV void gld16(const void* g, void* l) {
  const __attribute__((address_space(1))) unsigned* gp =
      (const __attribute__((address_space(1))) unsigned*)(uintptr_t)g;
  __attribute__((address_space(3))) unsigned* lp =
      (__attribute__((address_space(3))) unsigned*)(unsigned)(uintptr_t)l;
  __builtin_amdgcn_global_load_lds(gp, lp, 16, 0, 0);
}

// ---------------- weight transpose + cast: W[R][C] f32 -> Wt[C][R] bf16 ---------------
__global__ __launch_bounds__(256) void k_transpose_cast(
    const float* __restrict__ W, bf16_t* __restrict__ Wt, int R, int C) {
  __shared__ float tile[32][33];
  const int bx = blockIdx.x * 32;           // C-dim base
  const int by = blockIdx.y * 32;           // R-dim base
  const int tx = threadIdx.x & 31, ty = threadIdx.x >> 5;  // 32 x 8
#pragma unroll
  for (int i = 0; i < 32; i += 8)
    tile[ty + i][tx] = W[(size_t)(by + ty + i) * C + (bx + tx)];
  __syncthreads();
#pragma unroll
  for (int i = 0; i < 32; i += 8)
    Wt[(size_t)(bx + ty + i) * R + (by + tx)] = __float2bfloat16(tile[tx][ty + i]);
}

// -------- fused LN(+stats)+shift+time-mix -> xk/xv/xr (bf16); one block per row --------
__global__ __launch_bounds__(256) void k_ln1f(
    const float* __restrict__ X, const float* __restrict__ g, const float* __restrict__ be,
    const float* __restrict__ mk, const float* __restrict__ mv, const float* __restrict__ mr,
    bf16_t* __restrict__ ok, bf16_t* __restrict__ ov, bf16_t* __restrict__ orr) {
  const int row = blockIdx.x;
  const int l = row & (kL - 1);
  const int i = threadIdx.x;                 // 4 floats per thread
  const bool hp = (l != 0);
  float xa[4], pa[4] = {0.f, 0.f, 0.f, 0.f};
  *(float4*)xa = ((const float4*)(X + (size_t)row * kD))[i];
  if (hp) *(float4*)pa = ((const float4*)(X + (size_t)(row - 1) * kD))[i];
  float s0 = xa[0] + xa[1] + xa[2] + xa[3];
  float q0 = xa[0] * xa[0] + xa[1] * xa[1] + xa[2] * xa[2] + xa[3] * xa[3];
  float s1 = pa[0] + pa[1] + pa[2] + pa[3];
  float q1 = pa[0] * pa[0] + pa[1] * pa[1] + pa[2] * pa[2] + pa[3] * pa[3];
#pragma unroll
  for (int off = 32; off > 0; off >>= 1) {
    s0 += __shfl_xor(s0, off); q0 += __shfl_xor(q0, off);
    s1 += __shfl_xor(s1, off); q1 += __shfl_xor(q1, off);
  }
  __shared__ float red[4][4];
  const int wid = i >> 6, lane = i & 63;
  if (lane == 0) { red[wid][0] = s0; red[wid][1] = q0; red[wid][2] = s1; red[wid][3] = q1; }
  __syncthreads();
  s0 = red[0][0] + red[1][0] + red[2][0] + red[3][0];
  q0 = red[0][1] + red[1][1] + red[2][1] + red[3][1];
  s1 = red[0][2] + red[1][2] + red[2][2] + red[3][2];
  q1 = red[0][3] + red[1][3] + red[2][3] + red[3][3];
  const float m0 = s0 * (1.f / kD);
  const float r0 = rsqrtf(fmaxf(q0 * (1.f / kD) - m0 * m0, 0.f) + 1e-5f);
  const float m1 = s1 * (1.f / kD);
  const float r1 = rsqrtf(fmaxf(q1 * (1.f / kD) - m1 * m1, 0.f) + 1e-5f);
  float ga[4], ba[4], ka[4], va[4], ra[4];
  *(float4*)ga = ((const float4*)g)[i];
  *(float4*)ba = ((const float4*)be)[i];
  *(float4*)ka = ((const float4*)mk)[i];
  *(float4*)va = ((const float4*)mv)[i];
  *(float4*)ra = ((const float4*)mr)[i];
  ushort4 uk, uv, ur;
  unsigned short* pk = (unsigned short*)&uk;
  unsigned short* pv = (unsigned short*)&uv;
  unsigned short* pr = (unsigned short*)&ur;
#pragma unroll
  for (int c = 0; c < 4; ++c) {
    float xn = (xa[c] - m0) * r0 * ga[c] + ba[c];
    float xp = hp ? (pa[c] - m1) * r1 * ga[c] + ba[c] : 0.f;   // shift: row 0 -> zeros
    pk[c] = f2bf(xn * ka[c] + xp * (1.f - ka[c]));
    pv[c] = f2bf(xn * va[c] + xp * (1.f - va[c]));
    pr[c] = f2bf(xn * ra[c] + xp * (1.f - ra[c]));
  }
  ((ushort4*)(ok + (size_t)row * kD))[i] = uk;
  ((ushort4*)(ov + (size_t)row * kD))[i] = uv;
  ((ushort4*)(orr + (size_t)row * kD))[i] = ur;
}

// ---- fused LN(+stats)+shift for channel mix, bf16 input x1: ymix=0.5(yn+yp), ynb=yn ----
__global__ __launch_bounds__(256) void k_ln2fb(
    const bf16_t* __restrict__ X, const float* __restrict__ g, const float* __restrict__ be,
    bf16_t* __restrict__ om, bf16_t* __restrict__ on) {
  const int row = blockIdx.x;
  const int l = row & (kL - 1);
  const int i = threadIdx.x;
  const bool hp = (l != 0);
  ushort4 xu = ((const ushort4*)(X + (size_t)row * kD))[i];
  ushort4 pu = make_ushort4(0, 0, 0, 0);
  if (hp) pu = ((const ushort4*)(X + (size_t)(row - 1) * kD))[i];
  float xa[4], pa[4];
  xa[0] = bf2f(xu.x); xa[1] = bf2f(xu.y); xa[2] = bf2f(xu.z); xa[3] = bf2f(xu.w);
  pa[0] = bf2f(pu.x); pa[1] = bf2f(pu.y); pa[2] = bf2f(pu.z); pa[3] = bf2f(pu.w);
  float s0 = xa[0] + xa[1] + xa[2] + xa[3];
  float q0 = xa[0] * xa[0] + xa[1] * xa[1] + xa[2] * xa[2] + xa[3] * xa[3];
  float s1 = pa[0] + pa[1] + pa[2] + pa[3];
  float q1 = pa[0] * pa[0] + pa[1] * pa[1] + pa[2] * pa[2] + pa[3] * pa[3];
#pragma unroll
  for (int off = 32; off > 0; off >>= 1) {
    s0 += __shfl_xor(s0, off); q0 += __shfl_xor(q0, off);
    s1 += __shfl_xor(s1, off); q1 += __shfl_xor(q1, off);
  }
  __shared__ float red[4][4];
  const int wid = i >> 6, lane = i & 63;
  if (lane == 0) { red[wid][0] = s0; red[wid][1] = q0; red[wid][2] = s1; red[wid][3] = q1; }
  __syncthreads();
  s0 = red[0][0] + red[1][0] + red[2][0] + red[3][0];
  q0 = red[0][1] + red[1][1] + red[2][1] + red[3][1];
  s1 = red[0][2] + red[1][2] + red[2][2] + red[3][2];
  q1 = red[0][3] + red[1][3] + red[2][3] + red[3][3];
  const float m0 = s0 * (1.f / kD);
  const float r0 = rsqrtf(fmaxf(q0 * (1.f / kD) - m0 * m0, 0.f) + 1e-5f);
  const float m1 = s1 * (1.f / kD);
  const float r1 = rsqrtf(fmaxf(q1 * (1.f / kD) - m1 * m1, 0.f) + 1e-5f);
  float ga[4], ba[4];
  *(float4*)ga = ((const float4*)g)[i];
  *(float4*)ba = ((const float4*)be)[i];
  ushort4 um, un;
  unsigned short* qm = (unsigned short*)&um;
  unsigned short* qn = (unsigned short*)&un;
#pragma unroll
  for (int c = 0; c < 4; ++c) {
    float yn = (xa[c] - m0) * r0 * ga[c] + ba[c];
    float yp = hp ? (pa[c] - m1) * r1 * ga[c] + ba[c] : 0.f;
    qm[c] = f2bf(0.5f * (yn + yp));
    qn[c] = f2bf(yn);
  }
  ((ushort4*)(om + (size_t)row * kD))[i] = um;
  ((ushort4*)(on + (size_t)row * kD))[i] = un;
}

// ===================== WKV: segmented parallel scan over L =====================
__global__ __launch_bounds__(256) void k_wkv_seg(
    const unsigned short* __restrict__ kq, const unsigned short* __restrict__ vq,
    const float* __restrict__ td, const float* __restrict__ tf,
    float* __restrict__ segA, float* __restrict__ segB) {
  const int d = blockIdx.x * 256 + threadIdx.x;
  const int b = blockIdx.y;
  const int s = blockIdx.z;
  const float ew = __expf(-__expf(td[d]));
  const float uu = (s == 0) ? tf[d] : 0.f;
  const size_t base = ((size_t)b * kL + (size_t)s * kP) * kD + d;
  float a = 0.f, bb = 0.f;
  unsigned short kA[16], vA[16], kB[16], vB[16];
  auto pref = [&](unsigned short* ka, unsigned short* va, int c) {
    const size_t o0 = base + (size_t)c * 16 * kD;
#pragma unroll
    for (int j = 0; j < 16; ++j) {
      ka[j] = kq[o0 + (size_t)j * kD];
      va[j] = vq[o0 + (size_t)j * kD];
    }
  };
  auto comp = [&](const unsigned short* ka, const unsigned short* va, int c) {
#pragma unroll
    for (int j = 0; j < 16; ++j) {
      float kf = bf2f(ka[j]);
      if (s == 0 && c == 0 && j == 0) kf += uu;    // t==0: exp(u + k0)
      float ek = __expf(kf);
      a = ew * a + ek * bf2f(va[j]);
      bb = ew * bb + ek;
    }
  };
  pref(kA, vA, 0);
  pref(kB, vB, 1); comp(kA, vA, 0);
  pref(kA, vA, 2); comp(kB, vB, 1);
  pref(kB, vB, 3); comp(kA, vA, 2);
  comp(kB, vB, 3);
  const size_t sidx = ((size_t)b * kSeg + s) * kD + d;
  segA[sidx] = a;
  segB[sidx] = bb;
}

__global__ __launch_bounds__(256) void k_wkv_carry(
    const float* __restrict__ td,
    const float* __restrict__ segA, const float* __restrict__ segB,
    float* __restrict__ carA, float* __restrict__ carB) {
  const int d = blockIdx.x * 256 + threadIdx.x;
  const int b = blockIdx.y;
  const float ew = __expf(-__expf(td[d]));
  float ewP = ew;
#pragma unroll
  for (int i = 0; i < 6; ++i) ewP *= ewP;          // ew^64
  float ca = 0.f, cb = 0.f;
#pragma unroll 4
  for (int s = 0; s < kSeg; ++s) {
    const size_t idx = ((size_t)b * kSeg + s) * kD + d;
    carA[idx] = ca;
    carB[idx] = cb;
    ca = ewP * ca + segA[idx];
    cb = ewP * cb + segB[idx];
  }
}

__global__ __launch_bounds__(256) void k_wkv_out(
    const unsigned short* __restrict__ kq, const unsigned short* __restrict__ vq,
    const unsigned short* __restrict__ rq, const float* __restrict__ td,
    const float* __restrict__ tf, const float* __restrict__ carA,
    const float* __restrict__ carB, unsigned short* __restrict__ out) {
  const int d = blockIdx.x * 256 + threadIdx.x;
  const int b = blockIdx.y;
  const int s = blockIdx.z;
  const float ew = __expf(-__expf(td[d]));
  const float uu = (s == 0) ? tf[d] : 0.f;
  const size_t base = ((size_t)b * kL + (size_t)s * kP) * kD + d;
  const size_t sidx = ((size_t)b * kSeg + s) * kD + d;
  float a = carA[sidx], bb = carB[sidx];
  unsigned short kA[16], vA[16], rA[16], kB[16], vB[16], rB[16];
  auto pref = [&](unsigned short* ka, unsigned short* va, unsigned short* ra, int c) {
    const size_t o0 = base + (size_t)c * 16 * kD;
#pragma unroll
    for (int j = 0; j < 16; ++j) {
      ka[j] = kq[o0 + (size_t)j * kD];
      va[j] = vq[o0 + (size_t)j * kD];
      ra[j] = rq[o0 + (size_t)j * kD];
    }
  };
  auto comp = [&](const unsigned short* ka, const unsigned short* va,
                  const unsigned short* ra, int c) {
    const size_t o0 = base + (size_t)c * 16 * kD;
#pragma unroll
    for (int j = 0; j < 16; ++j) {
      float kf = bf2f(ka[j]);
      if (s == 0 && c == 0 && j == 0) kf += uu;
      float ek = __expf(kf);
      a = ew * a + ek * bf2f(va[j]);
      bb = ew * bb + ek;
      float y = a / (bb + 1e-8f);
      float sr = 1.f / (1.f + __expf(-bf2f(ra[j])));
      out[o0 + (size_t)j * kD] = f2bf(sr * y);
    }
  };
  pref(kA, vA, rA, 0);
  pref(kB, vB, rB, 1); comp(kA, vA, rA, 0);
  pref(kA, vA, rA, 2); comp(kB, vB, rB, 1);
  pref(kB, vB, rB, 3); comp(kA, vA, rA, 2);
  comp(kB, vB, rB, 3);
}

// ====== bf16 MFMA GEMM: BM=BN=256 BK=64, 8 waves of 128x64, 16x16x32 (R8 loop) ======
// R8's verified structure: A+B via LDS (dbuf 2x64KB), one barrier + lgkm(0) +
// vmcnt(0) per K-tile, T1 XCD bands, T2 XOR swizzle (16-row frag reads = 2-way
// bank alias = free; 32x32 shape was 4-way, R12 falsified), T5 setprio.
// EPI: 0 bf16 store, 1 bf16(addf + acc) [x1b], 2 relu(acc)^2, 3 sigmoid,
//      4 f32 store acc, 6 f32 addb(bf16) + mulb*(Cf+acc) [final combine]
template <int EPI>
__global__ __launch_bounds__(512, 2) void gemmT(
    const bf16_t* __restrict__ A0, long strA, int lda,
    const bf16_t* __restrict__ B0, long strB, int ldb,
    bf16_t* __restrict__ Cb0, float* __restrict__ Cf, long strC,
    int N, int K, int nbx,
    const float* __restrict__ addf, const bf16_t* __restrict__ addb,
    const bf16_t* __restrict__ mulb) {
  __shared__ __align__(16) char lds[131072];   // 2 x (A[256][64]bf16 @0 + B[256][64] @32768)
  const int z = blockIdx.z;
  const bf16_t* A = A0 + (size_t)z * strA;
  const bf16_t* Bt = B0 + (size_t)z * strB;
  const int nwg = gridDim.x;
  const int wg = (blockIdx.x & 7) * (nwg >> 3) + (blockIdx.x >> 3);
  const int by = wg / nbx, bx = wg - by * nbx;
  const long brow = (long)by * 256;
  const long bcol = (long)bx * 256;
  const int tid = threadIdx.x;
  const int lane = tid & 63;
  const int wid = tid >> 6;
  const int wr = wid >> 2, wc = wid & 3;   // 2 x 4 waves, each owns 128x64 out

  f32x4 acc[8][4] = {};

  // staging: thread covers 16B at (row = q*64 + tid>>3, slot = (tid&7)*16)
  const int trow = tid >> 3;
  const int scol = ((tid & 7) * 16) ^ ((trow & 7) << 4);   // pre-swizzled source col
  const char* Ag = (const char*)(A + (brow + trow) * (size_t)lda) + scol;
  const char* Bg = (const char*)(Bt + (bcol + trow) * (size_t)ldb) + scol;
  const long rsA = 64L * lda * 2;
  const long rsB = 64L * ldb * 2;

#define STAGE(kt, p)                                   \
  {                                                    \
    const long kb = (long)(kt) * 128;                  \
    char* Ld = lds + (p) * 65536 + tid * 16;           \
    gld16(Ag + kb, Ld);                                \
    gld16(Ag + kb + rsA, Ld + 8192);                   \
    gld16(Ag + kb + 2 * rsA, Ld + 16384);              \
    gld16(Ag + kb + 3 * rsA, Ld + 24576);              \
    gld16(Bg + kb, Ld + 32768);                        \
    gld16(Bg + kb + rsB, Ld + 40960);                  \
    gld16(Bg + kb + 2 * rsB, Ld + 49152);              \
    gld16(Bg + kb + 3 * rsB, Ld + 57344);              \
  }

  // fragment reads (swizzled): row r, logical byte-col c -> c ^ ((r&7)<<4)
  const int l16 = lane & 15, kq = lane >> 4;
  const int swz = (l16 & 7) << 4;
  const int oS0 = (kq * 16) ^ swz;          // K-slice 0 (k 0..31)
  const int oS1 = (64 + kq * 16) ^ swz;     // K-slice 1 (k 32..63)
  const char* Arow = lds + (wr * 128 + l16) * 128;           // A frag m: +m*2048
  const char* Brow = lds + 32768 + (wc * 64 + l16) * 128;    // B frag n: +n*2048

  bf16x8 aE[8], bE[4], aO[8], bO[4];
  const int NT = K >> 6;

  STAGE(0, 0) STAGE(1, 1)
  asm volatile("s_waitcnt vmcnt(8)" ::: "memory");   // STAGE(0) landed (intrinsics ordered)
  __builtin_amdgcn_s_barrier();
#pragma unroll
  for (int m = 0; m < 8; ++m) aE[m] = *(const bf16x8*)(Arow + m * 2048 + oS0);
#pragma unroll
  for (int n = 0; n < 4; ++n) bE[n] = *(const bf16x8*)(Brow + n * 2048 + oS0);

  for (int t = 0; t < NT; ++t) {
    const int p = t & 1;
    const char* Ap = Arow + p * 65536;
    const char* Bp = Brow + p * 65536;
    // issue reads of slice1 (consumed by the NEXT cluster); pin above MFMA
#pragma unroll
    for (int m = 0; m < 8; ++m) aO[m] = *(const bf16x8*)(Ap + m * 2048 + oS1);
#pragma unroll
    for (int n = 0; n < 4; ++n) bO[n] = *(const bf16x8*)(Bp + n * 2048 + oS1);
    __builtin_amdgcn_sched_barrier(0);
    __builtin_amdgcn_s_setprio(1);
#pragma unroll
    for (int m = 0; m < 8; ++m)
#pragma unroll
      for (int n = 0; n < 4; ++n)
        acc[m][n] = __builtin_amdgcn_mfma_f32_16x16x32_bf16(aE[m], bE[n], acc[m][n], 0, 0, 0);
    __builtin_amdgcn_s_setprio(0);
    asm volatile("s_waitcnt lgkmcnt(0)" ::: "memory");   // my reads of buf p done
    asm volatile("s_waitcnt vmcnt(0)" ::: "memory");     // STAGE(t+1) landed (1 tile old)
    __builtin_amdgcn_s_barrier();                        // p free to overwrite; 1-p ready
    if (t + 2 < NT) STAGE(t + 2, p)
    if (t + 1 < NT) {
      const char* An = Arow + (1 - p) * 65536;
      const char* Bn = Brow + (1 - p) * 65536;
#pragma unroll
      for (int m = 0; m < 8; ++m) aE[m] = *(const bf16x8*)(An + m * 2048 + oS0);
#pragma unroll
      for (int n = 0; n < 4; ++n) bE[n] = *(const bf16x8*)(Bn + n * 2048 + oS0);
    }
    __builtin_amdgcn_sched_barrier(0);
    __builtin_amdgcn_s_setprio(1);
#pragma unroll
    for (int m = 0; m < 8; ++m)
#pragma unroll
      for (int n = 0; n < 4; ++n)
        acc[m][n] = __builtin_amdgcn_mfma_f32_16x16x32_bf16(aO[m], bO[n], acc[m][n], 0, 0, 0);
    __builtin_amdgcn_s_setprio(0);
  }
#undef STAGE

  bf16_t* Cb = Cb0 + (size_t)z * strC;
  const long orow = brow + wr * 128 + (lane >> 4) * 4;  // C/D: col=lane&15, row=(lane>>4)*4+reg
  const long ocol = bcol + wc * 64 + l16;
#pragma unroll
  for (int m = 0; m < 8; ++m) {
#pragma unroll
    for (int reg = 0; reg < 4; ++reg) {
      const long r = orow + m * 16 + reg;
#pragma unroll
      for (int n = 0; n < 4; ++n) {
        const size_t idx = (size_t)r * N + ocol + n * 16;
        const float v = acc[m][n][reg];
        if constexpr (EPI == 0) {
          Cb[idx] = __float2bfloat16(v);
        } else if constexpr (EPI == 1) {
          Cb[idx] = __float2bfloat16(addf[idx] + v);
        } else if constexpr (EPI == 2) {
          float u = v > 0.f ? v : 0.f;
          Cb[idx] = __float2bfloat16(u * u);
        } else if constexpr (EPI == 3) {
          Cb[idx] = __float2bfloat16(1.f / (1.f + __expf(-v)));
        } else if constexpr (EPI == 4) {
          Cf[idx] = v;
        } else {
          Cf[idx] = __bfloat162float(addb[idx]) + __bfloat162float(mulb[idx]) * (Cf[idx] + v);
        }
      }
    }
  }
}

extern "C" void kernel_launch(void* const* d_in, const int* in_sizes, int n_in,
                              void* d_out, int out_size, void* d_ws, size_t ws_size,
                              hipStream_t stream) {
  const float* x    = (const float*)d_in[0];
  const float* ln1g = (const float*)d_in[1];
  const float* ln1b = (const float*)d_in[2];
  const float* Wk   = (const float*)d_in[3];
  const float* Wv   = (const float*)d_in[4];
  const float* Wr   = (const float*)d_in[5];
  const float* Wo   = (const float*)d_in[6];
  const float* td   = (const float*)d_in[7];
  const float* tf   = (const float*)d_in[8];
  const float* mk   = (const float*)d_in[9];
  const float* mv   = (const float*)d_in[10];
  const float* mr   = (const float*)d_in[11];
  const float* ln2g = (const float*)d_in[12];
  const float* ln2b = (const float*)d_in[13];
  const float* Wfk  = (const float*)d_in[14];
  const float* Wfv  = (const float*)d_in[15];
  const float* Wfr  = (const float*)d_in[16];

  char* ws = (char*)d_ws;
  const size_t MB = 1ull << 20;
  bf16_t* WkT  = (bf16_t*)(ws + 0 * MB);
  bf16_t* WvT  = (bf16_t*)(ws + 2 * MB);
  bf16_t* WrT  = (bf16_t*)(ws + 4 * MB);
  bf16_t* WoT  = (bf16_t*)(ws + 6 * MB);
  bf16_t* WfkT = (bf16_t*)(ws + 8 * MB);    // [4096][1024]
  bf16_t* WfvT = (bf16_t*)(ws + 16 * MB);   // [1024][4096]
  bf16_t* WfrT = (bf16_t*)(ws + 24 * MB);
  bf16_t* xk   = (bf16_t*)(ws + 28 * MB);
  bf16_t* xv   = (bf16_t*)(ws + 60 * MB);
  bf16_t* xr   = (bf16_t*)(ws + 92 * MB);
  bf16_t* kbuf = (bf16_t*)(ws + 124 * MB);
  bf16_t* vbuf = (bf16_t*)(ws + 156 * MB);
  bf16_t* rbuf = (bf16_t*)(ws + 188 * MB);
  float*  segA = (float*)(ws + 60 * MB);
  float*  segB = (float*)(ws + 61 * MB);
  float*  carA = (float*)(ws + 62 * MB);
  float*  carB = (float*)(ws + 63 * MB);
  bf16_t* rwkv = (bf16_t*)(ws + 92 * MB);
  bf16_t* x1b  = (bf16_t*)(ws + 28 * MB);   // bf16 residual, 32 MB
  bf16_t* rr   = (bf16_t*)(ws + 92 * MB);
  bf16_t* ynb  = (bf16_t*)(ws + 124 * MB);
  bf16_t* kk   = (bf16_t*)(ws + 124 * MB);  // [16384][2048] bf16 = 64 MB
  bf16_t* ymix = (bf16_t*)(ws + 188 * MB);
  float*  out  = (float*)d_out;
  const long sX = (long)kM * kD;            // 16777216 elems
  const long sW = (long)kD * kD;            // 1048576 elems

  dim3 blk(256), blkg(512);
  // weights -> bf16 B^T
  k_transpose_cast<<<dim3(32, 32), blk, 0, stream>>>(Wk, WkT, 1024, 1024);
  k_transpose_cast<<<dim3(32, 32), blk, 0, stream>>>(Wv, WvT, 1024, 1024);
  k_transpose_cast<<<dim3(32, 32), blk, 0, stream>>>(Wr, WrT, 1024, 1024);
  k_transpose_cast<<<dim3(32, 32), blk, 0, stream>>>(Wo, WoT, 1024, 1024);
  k_transpose_cast<<<dim3(128, 32), blk, 0, stream>>>(Wfk, WfkT, 1024, 4096);
  k_transpose_cast<<<dim3(32, 128), blk, 0, stream>>>(Wfv, WfvT, 4096, 1024);
  k_transpose_cast<<<dim3(32, 32), blk, 0, stream>>>(Wfr, WfrT, 1024, 1024);

  // ---- time mixing ----
  k_ln1f<<<kM, blk, 0, stream>>>(x, ln1g, ln1b, mk, mv, mr, xk, xv, xr);
  gemmT<0><<<dim3(256, 1, 3), blkg, 0, stream>>>(xk, sX, 1024, WkT, sW, 1024,
      kbuf, nullptr, sX, 1024, 1024, 4, nullptr, nullptr, nullptr);
  k_wkv_seg<<<dim3(4, 8, kSeg), blk, 0, stream>>>((const unsigned short*)kbuf,
      (const unsigned short*)vbuf, td, tf, segA, segB);
  k_wkv_carry<<<dim3(4, 8), blk, 0, stream>>>(td, segA, segB, carA, carB);
  k_wkv_out<<<dim3(4, 8, kSeg), blk, 0, stream>>>((const unsigned short*)kbuf,
      (const unsigned short*)vbuf, (const unsigned short*)rbuf, td, tf, carA, carB,
      (unsigned short*)rwkv);
  gemmT<1><<<256, blkg, 0, stream>>>(rwkv, 0, 1024, WoT, 0, 1024,
      x1b, nullptr, 0, 1024, 1024, 4, x, nullptr, nullptr);

  // ---- channel mixing ----
  k_ln2fb<<<kM, blk, 0, stream>>>(x1b, ln2g, ln2b, ymix, ynb);
  gemmT<3><<<256, blkg, 0, stream>>>(ynb, 0, 1024, WfrT, 0, 1024,
      rr, nullptr, 0, 1024, 1024, 4, nullptr, nullptr, nullptr);
  // hidden dim in 2 chunks of 2048: kk = relu(ymix@Wfk[:,c])^2; out (+)= kk@Wfv[c,:]
  for (int c = 0; c < 2; ++c) {
    gemmT<2><<<512, blkg, 0, stream>>>(ymix, 0, 1024, WfkT + (size_t)c * 2048 * 1024, 0, 1024,
        kk, nullptr, 0, 2048, 1024, 8, nullptr, nullptr, nullptr);
    if (c == 0)
      gemmT<4><<<256, blkg, 0, stream>>>(kk, 0, 2048, WfvT + 0, 0, 4096,
          nullptr, out, 0, 1024, 2048, 4, nullptr, nullptr, nullptr);
    else
      gemmT<6><<<256, blkg, 0, stream>>>(kk, 0, 2048, WfvT + 2048, 0, 4096,
          nullptr, out, 0, 1024, 2048, 4, nullptr, x1b, rr);
  }
}